// Round 12
// baseline (27285.965 us; speedup 1.0000x reference)
//
#include <hip/hip_runtime.h>
#include <math.h>

// ---------------------------------------------------------------------------
// CurvePredictor R12: continuous cross-barrier weight pipeline.
// 64 blocks x 256 threads (VGPR budget ~236 = 65536/256, law pinned R1-R11),
// 32 batch rows/block, wave owns 4 hidden 16-col slices. Weights L2-resident.
// Key change vs R10: the in-step barriers are RAW (s_waitcnt lgkmcnt(0) +
// s_barrier) so global weight loads stay in flight across them, and all GEMMs
// run one rolling ring of 8-frag batches (issue k+2 / consume k) that threads
// A -> B -> C and hands the next step's head batches + xp across the step
// boundary. The stream never drains; exposed L2 latency amortizes away.
// c-state in LDS; xp streamed from d_ws f32 scratch; W4 register-resident.
// ---------------------------------------------------------------------------

typedef short s8v __attribute__((ext_vector_type(8)));   // 8 x bf16
typedef float f4v __attribute__((ext_vector_type(4)));   // 4 x f32

#define HSTR 264            // LDS h-row stride in shorts (33*16B)
#define DSTR 136
#define XP_OFF 2166784u     // byte offset of xp scratch in d_ws

__device__ __forceinline__ f4v mfma16(s8v a, s8v b, f4v c){
  return __builtin_amdgcn_mfma_f32_16x16x32_bf16(a, b, c, 0, 0, 0);
}
__device__ __forceinline__ short f2bf(float f){
  unsigned u = __float_as_uint(f);
  u = u + 0x7FFFu + ((u >> 16) & 1u);
  return (short)(u >> 16);
}
__device__ __forceinline__ float wred(float v){
  #pragma unroll
  for (int o = 32; o; o >>= 1) v += __shfl_xor(v, o);
  return v;
}
__device__ __forceinline__ float sigm(float x){ return 1.0f / (1.0f + __expf(-x)); }
__device__ __forceinline__ float tnh(float x){
  x = fminf(15.0f, fmaxf(-15.0f, x));
  float e = __expf(2.0f * x);
  return (e - 1.0f) / (e + 1.0f);
}
__device__ __forceinline__ float gelu(float v){
  return 0.5f * v * (1.0f + erff(v * 0.70710678118654752440f));
}

// Raw workgroup barrier: drain LDS ops only; global loads stay in flight.
__device__ __forceinline__ void wgb(){
  __builtin_amdgcn_s_waitcnt(0xC07F);      // lgkmcnt(0) only
  __asm__ volatile("" ::: "memory");
  __builtin_amdgcn_s_barrier();
  __asm__ volatile("" ::: "memory");
}

// ws layout (shorts), swizzled (same as R5-R11):
// main matrices (1024x256): elem = s*16384 + g*4096 + kk*512 + lane*8 + j
//   [0,262144) Wih0  [262144,524288) Whh0  [524288,786432) Wih1  [786432,1048576) Whh1
// W3 [128][256]: 1048576 + s2*4096 + kk*512 + lane*8
// W4 padded [16][128]: 1081344 + kk*512 + lane*8
// then at byte XP_OFF: f32 xp scratch, 128KB per block.
__global__ void prep_kernel(
    const float* __restrict__ Wih0, const float* __restrict__ Whh0,
    const float* __restrict__ Wih1, const float* __restrict__ Whh1,
    const float* __restrict__ W3,   const float* __restrict__ W4,
    short* __restrict__ wsb)
{
  const int i = blockIdx.x * 256 + threadIdx.x;
  if (i >= 1083392) return;
  float v;
  if (i < 1048576){
    const int seg = i >> 18;
    const int r   = i & 262143;
    const int s   = r >> 14;
    const int g   = (r >> 12) & 3;
    const int kk  = (r >> 9) & 7;
    const int q   = (r >> 7) & 3;
    const int m16 = (r >> 3) & 15;
    const int j   = r & 7;
    const int hid = s * 16 + m16;
    const int k   = kk * 32 + q * 8 + j;
    const float* mt = (seg == 0) ? Wih0 : (seg == 1) ? Whh0 : (seg == 2) ? Wih1 : Whh1;
    v = mt[(g * 256 + hid) * 256 + k];
  } else if (i < 1081344){
    const int r   = i - 1048576;
    const int s2  = r >> 12;
    const int kk  = (r >> 9) & 7;
    const int q   = (r >> 7) & 3;
    const int m16 = (r >> 3) & 15;
    const int j   = r & 7;
    v = W3[(s2 * 16 + m16) * 256 + kk * 32 + q * 8 + j];
  } else {
    const int r   = i - 1081344;
    const int kk  = (r >> 9) & 3;
    const int q   = (r >> 7) & 3;
    const int m16 = (r >> 3) & 15;
    const int j   = r & 7;
    const int k   = kk * 32 + q * 8 + j;
    v = (m16 < 2) ? W4[m16 * 128 + k] : 0.0f;
  }
  wsb[i] = f2bf(v);
}

struct B8 { s8v f[8]; };   // one 8-frag batch: kk-pair x 4 gates (32 VGPR)

__device__ __forceinline__ void ld8(B8& b, const short* __restrict__ pw, int kp){
  #pragma unroll
  for (int g = 0; g < 4; g++)
    #pragma unroll
    for (int i = 0; i < 2; i++)
      b.f[g * 2 + i] = *(const s8v*)(pw + g * 4096 + (kp * 2 + i) * 512);
}
__device__ __forceinline__ void cs8(const B8& b, const short* __restrict__ hA,
                                    int kp, int m16, int q, f4v (&acc)[2][4]){
  #pragma unroll
  for (int i = 0; i < 2; i++){
    const int kk = kp * 2 + i;
    const s8v a0 = *(const s8v*)&hA[ m16       * HSTR + kk * 32 + q * 8];
    const s8v a1 = *(const s8v*)&hA[(16 + m16) * HSTR + kk * 32 + q * 8];
    #pragma unroll
    for (int g = 0; g < 4; g++){
      acc[0][g] = mfma16(a0, b.f[g * 2 + i], acc[0][g]);
      acc[1][g] = mfma16(a1, b.f[g * 2 + i], acc[1][g]);
    }
  }
}

__global__ __launch_bounds__(256, 1) void curve_main(
    const float* __restrict__ x,
    const float* __restrict__ W1, const float* __restrict__ b1,
    const float* __restrict__ g1, const float* __restrict__ be1,
    const float* __restrict__ W2, const float* __restrict__ b2,
    const float* __restrict__ g2, const float* __restrict__ be2,
    const float* __restrict__ bih0, const float* __restrict__ bhh0,
    const float* __restrict__ bih1, const float* __restrict__ bhh1,
    const float* __restrict__ b3, const float* __restrict__ b4,
    const short* __restrict__ wsb, float* __restrict__ xpg,
    float* __restrict__ out)
{
  const int tid  = threadIdx.x;
  const int w    = tid >> 6;        // wave 0..3, owns slices 4w..4w+3
  const int lane = tid & 63;
  const int q    = lane >> 4;
  const int m16  = lane & 15;
  const int row0 = blockIdx.x * 32;

  __shared__ __align__(16) short h0b[2][32 * HSTR];
  __shared__ __align__(16) short h1b[2][32 * HSTR];
  __shared__ __align__(16) short dstg[32 * DSTR];
  __shared__ __align__(16) float csh[64 * 256];   // c-state: idx*256 + tid

  // --------- encoder: wave w computes batch rows row0 + u*4 + w ------------
  #pragma unroll 1
  for (int u = 0; u < 8; u++){
    const int rr = u * 4 + w;
    const int r  = row0 + rr;
    float xv[5];
    #pragma unroll
    for (int k = 0; k < 5; k++) xv[k] = x[r * 5 + k];
    float a0 = b1[lane], a1 = b1[lane + 64];
    #pragma unroll
    for (int k = 0; k < 5; k++){
      a0 += xv[k] * W1[lane * 5 + k];
      a1 += xv[k] * W1[(lane + 64) * 5 + k];
    }
    a0 = gelu(a0); a1 = gelu(a1);
    float mean = wred(a0 + a1) * (1.0f / 128.0f);
    float d0 = a0 - mean, d1 = a1 - mean;
    float inv = rsqrtf(wred(d0 * d0 + d1 * d1) * (1.0f / 128.0f) + 1e-5f);
    float y0 = d0 * inv * g1[lane]      + be1[lane];
    float y1 = d1 * inv * g1[lane + 64] + be1[lane + 64];

    float acc2[4];
    #pragma unroll
    for (int uu = 0; uu < 4; uu++) acc2[uu] = b2[lane + 64 * uu];
    for (int k = 0; k < 64; k++){
      float v0 = __shfl(y0, k);
      float v1 = __shfl(y1, k);
      #pragma unroll
      for (int uu = 0; uu < 4; uu++){
        const float* wr = W2 + (lane + 64 * uu) * 128;
        acc2[uu] += v0 * wr[k] + v1 * wr[k + 64];
      }
    }
    #pragma unroll
    for (int uu = 0; uu < 4; uu++) acc2[uu] = gelu(acc2[uu]);
    float s = acc2[0] + acc2[1] + acc2[2] + acc2[3];
    mean = wred(s) * (1.0f / 256.0f);
    float vv = 0.0f;
    #pragma unroll
    for (int uu = 0; uu < 4; uu++){ float d = acc2[uu] - mean; vv += d * d; }
    inv = rsqrtf(wred(vv) * (1.0f / 256.0f) + 1e-5f);
    #pragma unroll
    for (int uu = 0; uu < 4; uu++){
      int c = lane + 64 * uu;
      float e = (acc2[uu] - mean) * inv * g2[c] + be2[c];
      h0b[0][rr * HSTR + c] = f2bf(e);       // enc staged in h0 slot 0
    }
  }
  __syncthreads();

  // swizzled bases (slice stride 16384 shorts), per-lane offset lane*16B
  const short* pwi0 = wsb            + (4 * w) * 16384 + (lane << 3);
  const short* pwh0 = wsb +  262144  + (4 * w) * 16384 + (lane << 3);
  const short* pwi1 = wsb +  524288  + (4 * w) * 16384 + (lane << 3);
  const short* pwh1 = wsb +  786432  + (4 * w) * 16384 + (lane << 3);
  const short* pw3  = wsb + 1048576  + (2 * w) * 4096 + (lane << 3);
  const short* pw4  = wsb + 1081344  + (lane << 3);
  float* xpw = xpg + blockIdx.x * 32768 + (4 * w) * 2048 + lane * 4;

  // ---- init: xp = enc @ Wih0^T + (bih0+bhh0) -> f32 scratch in d_ws ----
  #pragma unroll 1
  for (int s = 0; s < 4; s++){
    const short* pw = pwi0 + s * 16384;
    B8 P, Q;
    ld8(P, pw, 0); ld8(Q, pw, 1);
    f4v acc[2][4];
    #pragma unroll
    for (int g = 0; g < 4; g++){
      const int n = g * 256 + (4 * w + s) * 16 + m16;
      const float bi = bih0[n] + bhh0[n];
      f4v t = {bi, bi, bi, bi};
      acc[0][g] = t; acc[1][g] = t;
    }
    cs8(P, &h0b[0][0], 0, m16, q, acc);
    ld8(P, pw, 2);
    cs8(Q, &h0b[0][0], 1, m16, q, acc);
    ld8(Q, pw, 3);
    cs8(P, &h0b[0][0], 2, m16, q, acc);
    cs8(Q, &h0b[0][0], 3, m16, q, acc);
    float* xs = xpw + s * 2048;
    #pragma unroll
    for (int rt = 0; rt < 2; rt++)
      #pragma unroll
      for (int g = 0; g < 4; g++){
        float4 v4 = {acc[rt][g][0], acc[rt][g][1], acc[rt][g][2], acc[rt][g][3]};
        *(float4*)(xs + (rt * 4 + g) * 256) = v4;
      }
  }
  __syncthreads();
  for (int i = tid; i < 32 * HSTR; i += 256){ h0b[0][i] = 0; h1b[0][i] = 0; }
  for (int i = tid; i < 64 * 256; i += 256) csh[i] = 0.0f;

  // register-resident constants
  s8v w4f[4];
  #pragma unroll
  for (int kk = 0; kk < 4; kk++) w4f[kk] = *(const s8v*)(pw4 + kk * 512);
  float bs1[4][4];                        // [slice][gate]
  #pragma unroll
  for (int s = 0; s < 4; s++)
    #pragma unroll
    for (int g = 0; g < 4; g++){
      const int n = g * 256 + (4 * w + s) * 16 + m16;
      bs1[s][g] = bih1[n] + bhh1[n];
    }
  const float b3c0 = b3[(2 * w    ) * 16 + m16];
  const float b3c1 = b3[(2 * w + 1) * 16 + m16];
  const float b4v  = (m16 < 2) ? b4[m16] : 0.0f;
  __syncthreads();                        // last draining barrier

  // ---- pipeline state (persists across t) ----
  B8 ra[3], rb[3];
  s8v w3r[2][8];
  f4v xfv[8];
  ld8(ra[0], pwh0, 0);                    // A idx0 (slice0, kp0)
  ld8(ra[1], pwh0, 1);                    // A idx1
  #pragma unroll
  for (int jj = 0; jj < 8; jj++) xfv[jj] = *(const f4v*)(xpw + jj * 256);

  // --------------------------- recurrence over T ---------------------------
  #pragma unroll 1
  for (int t = 0; t < 256; t++){
    const short* h0in  = h0b[t & 1];
    short*       h0out = h0b[(t + 1) & 1];
    const short* h1in  = h1b[t & 1];
    short*       h1out = h1b[(t + 1) & 1];

    // ---- Phase A: gates0 = xp + h0_old @ Whh0^T (rolling ring) ----
    {
      f4v acc[2][4];
      #pragma unroll
      for (int idx = 0; idx < 16; idx++){
        const int s = idx >> 2, kp = idx & 3;
        if (kp == 0){
          #pragma unroll
          for (int rt = 0; rt < 2; rt++)
            #pragma unroll
            for (int g = 0; g < 4; g++){ f4v z = {0.f,0.f,0.f,0.f}; acc[rt][g] = z; }
        }
        if (idx < 14){
          ld8(ra[(idx + 2) % 3], pwh0 + ((idx + 2) >> 2) * 16384, (idx + 2) & 3);
        } else {
          ld8(rb[idx - 14], pwi1, idx - 14);         // B head: (s0,i1,kp0/1)
        }
        cs8(ra[idx % 3], h0in, kp, m16, q, acc);
        if (kp == 3){
          const int col = (4 * w + s) * 16 + m16;
          float* cp = &csh[(s * 8) * 256 + tid];
          #pragma unroll
          for (int rt = 0; rt < 2; rt++)
            #pragma unroll
            for (int r = 0; r < 4; r++){
              float cc = cp[(rt * 4 + r) * 256];
              float ii = sigm(acc[rt][0][r] + xfv[rt * 4 + 0][r]);
              float ff = sigm(acc[rt][1][r] + xfv[rt * 4 + 1][r]);
              float gg = tnh (acc[rt][2][r] + xfv[rt * 4 + 2][r]);
              float oo = sigm(acc[rt][3][r] + xfv[rt * 4 + 3][r]);
              cc = ff * cc + ii * gg;
              cp[(rt * 4 + r) * 256] = cc;
              h0out[(rt * 16 + q * 4 + r) * HSTR + col] = f2bf(oo * tnh(cc));
            }
          if (s < 3){                                // xp for next slice
            const float* xs = xpw + (s + 1) * 2048;
            #pragma unroll
            for (int jj = 0; jj < 8; jj++) xfv[jj] = *(const f4v*)(xs + jj * 256);
          }
        }
      }
    }
    wgb();                                           // (1) h0_new visible

    // ---- Phase B: gates1 = bias1 + h0_new@Wih1^T + h1_old@Whh1^T ----
    {
      f4v acc[2][4];
      #pragma unroll
      for (int ib = 0; ib < 32; ib++){
        const int s = ib >> 3, j = ib & 7;
        if (j == 0){
          #pragma unroll
          for (int g = 0; g < 4; g++){
            f4v tv = {bs1[s][g], bs1[s][g], bs1[s][g], bs1[s][g]};
            acc[0][g] = tv; acc[1][g] = tv;
          }
        }
        if (ib < 30){
          const int n = ib + 2, s2 = n >> 3, j2 = n & 7;
          const short* pm = ((j2 < 4) ? pwi1 : pwh1) + s2 * 16384;
          ld8(rb[n % 3], pm, j2 & 3);
        } else {
          const int cgi = ib - 30;                   // W3 halves
          #pragma unroll
          for (int f = 0; f < 8; f++)
            w3r[cgi][f] = *(const s8v*)(pw3 + cgi * 4096 + f * 512);
        }
        const short* hA = (j < 4) ? h0out : h1in;
        cs8(rb[ib % 3], hA, j & 3, m16, q, acc);
        if (j == 7){
          const int col = (4 * w + s) * 16 + m16;
          float* cp = &csh[(32 + s * 8) * 256 + tid];
          #pragma unroll
          for (int rt = 0; rt < 2; rt++)
            #pragma unroll
            for (int r = 0; r < 4; r++){
              float cc = cp[(rt * 4 + r) * 256];
              float ii = sigm(acc[rt][0][r]);
              float ff = sigm(acc[rt][1][r]);
              float gg = tnh (acc[rt][2][r]);
              float oo = sigm(acc[rt][3][r]);
              cc = ff * cc + ii * gg;
              cp[(rt * 4 + r) * 256] = cc;
              h1out[(rt * 16 + q * 4 + r) * HSTR + col] = f2bf(oo * tnh(cc));
            }
        }
      }
    }
    wgb();                                           // (2) h1_new visible

    // ---- Phase C: d = gelu(h1_new @ W3^T + b3); + issue next step's head ---
    {
      #pragma unroll
      for (int cgi = 0; cgi < 2; cgi++){
        const float bc = cgi ? b3c1 : b3c0;
        #pragma unroll
        for (int rt = 0; rt < 2; rt++){
          f4v ad = {bc, bc, bc, bc};
          #pragma unroll
          for (int kk = 0; kk < 8; kk++){
            const s8v a = *(const s8v*)&h1out[(rt * 16 + m16) * HSTR + kk * 32 + q * 8];
            ad = mfma16(a, w3r[cgi][kk], ad);
          }
          #pragma unroll
          for (int r = 0; r < 4; r++)
            dstg[(rt * 16 + q * 4 + r) * DSTR + (2 * w + cgi) * 16 + m16] =
                f2bf(gelu(ad[r]));
        }
      }
      // next step's stream head (crosses barrier 3 + Phase D in flight)
      ld8(ra[0], pwh0, 0);
      ld8(ra[1], pwh0, 1);
      #pragma unroll
      for (int jj = 0; jj < 8; jj++) xfv[jj] = *(const f4v*)(xpw + jj * 256);
    }
    wgb();                                           // (3) d visible

    // ---- Phase D: out = d @ W4^T + b4 (waves 0,1; rt = w) ----
    if (w < 2){
      const int rt = w;
      f4v ao = {0.f, 0.f, 0.f, 0.f};
      #pragma unroll
      for (int kk = 0; kk < 4; kk++){
        const s8v a = *(const s8v*)&dstg[(rt * 16 + m16) * DSTR + kk * 32 + q * 8];
        ao = mfma16(a, w4f[kk], ao);
      }
      if (m16 < 2){
        #pragma unroll
        for (int r = 0; r < 4; r++)
          out[((size_t)(row0 + rt * 16 + q * 4 + r) * 256 + t) * 2 + m16] = ao[r] + b4v;
      }
    }
  }
}

extern "C" void kernel_launch(void* const* d_in, const int* in_sizes, int n_in,
                              void* d_out, int out_size, void* d_ws, size_t ws_size,
                              hipStream_t stream)
{
  const float* x    = (const float*)d_in[0];
  const float* W1   = (const float*)d_in[1];
  const float* b1   = (const float*)d_in[2];
  const float* g1   = (const float*)d_in[3];
  const float* be1  = (const float*)d_in[4];
  const float* W2   = (const float*)d_in[5];
  const float* b2   = (const float*)d_in[6];
  const float* g2   = (const float*)d_in[7];
  const float* be2  = (const float*)d_in[8];
  const float* Wih0 = (const float*)d_in[9];
  const float* Whh0 = (const float*)d_in[10];
  const float* bih0 = (const float*)d_in[11];
  const float* bhh0 = (const float*)d_in[12];
  const float* Wih1 = (const float*)d_in[13];
  const float* Whh1 = (const float*)d_in[14];
  const float* bih1 = (const float*)d_in[15];
  const float* bhh1 = (const float*)d_in[16];
  const float* W3   = (const float*)d_in[17];
  const float* b3   = (const float*)d_in[18];
  const float* W4   = (const float*)d_in[19];
  const float* b4   = (const float*)d_in[20];

  short* wsb = (short*)d_ws;
  float* xpg = (float*)((char*)d_ws + XP_OFF);

  prep_kernel<<<4232, 256, 0, stream>>>(Wih0, Whh0, Wih1, Whh1, W3, W4, wsb);
  curve_main<<<64, 256, 0, stream>>>(x, W1, b1, g1, be1, W2, b2, g2, be2,
                                     bih0, bhh0, bih1, bhh1, b3, b4, wsb, xpg,
                                     (float*)d_out);
}